// Round 2
// baseline (656.351 us; speedup 1.0000x reference)
//
#include <hip/hip_runtime.h>

// NeuralODEFlow: z_{t+1} = z_t + mlp(z_t)*dt;  log_det -= trace_fd
// trace_fd = sum_j (mlp(z_new+H e_j)[j]*dt - mlp(z_old)[j]*dt)/H
//          = [sum_j (y_new_j - y_old_j)]*dt/H  +  (m1^T E m2)*dt   (piecewise-linear MLP)
// with E[u,v] = W2[u,v] * K[v,u],  K = W3 @ W1  (precomputed once per call).

#define HD 512
#define DD 64
#define NB 1024

// ---------------- E precompute + logdet zero ----------------
// grid 512 (v), block 512 (u). W3[v*64+j] uniform per block (s_load),
// W1[j*512+u] coalesced. E write uncoalesced but only 1 MB once per call.
__global__ __launch_bounds__(512) void k_prep(const float* __restrict__ W1,
    const float* __restrict__ W2, const float* __restrict__ W3,
    float* __restrict__ E, float* __restrict__ logdet) {
  int v = blockIdx.x;       // 0..511
  int u = threadIdx.x;      // 0..511
  if (v < 2) logdet[v * 512 + u] = 0.f;
  float s = 0.f;
#pragma unroll 8
  for (int j = 0; j < DD; ++j)
    s = fmaf(W3[v * DD + j], W1[j * HD + u], s);
  E[u * HD + v] = W2[u * HD + v] * s;
}

// ---------------- L1: z_new = z + yA*dt (fused) ; h1 = relu(z_new @ W1 + b1) -------------
// grid 2048 = 128 row-groups (8 rows) x 16 v-groups (32 cols); block 256.
__global__ __launch_bounds__(256) void k_l1(const float* __restrict__ zin,
    float* __restrict__ zout, const float* __restrict__ ya, float dt,
    const float* __restrict__ W1, const float* __restrict__ b1,
    float* __restrict__ h1) {
  __shared__ float zt[512];              // 8 rows x 64
  int bid = blockIdx.x;
  int r0 = (bid >> 4) << 3;              // row base
  int vb = bid & 15;
  int tid = threadIdx.x;
  for (int idx = tid; idx < 512; idx += 256) {
    float zv = zin[r0 * DD + idx];
    zv = fmaf(ya[r0 * DD + idx], dt, zv);   // Euler update (dt=0 on init pass)
    zt[idx] = zv;
    zout[r0 * DD + idx] = zv;               // benign duplicate writes across v-groups
  }
  __syncthreads();
  int rl = tid >> 5;                     // 0..7
  int v = (vb << 5) + (tid & 31);
  const float* zr = &zt[rl * DD];
  float acc = b1[v];
#pragma unroll 8
  for (int k = 0; k < DD; ++k) acc = fmaf(zr[k], W1[k * HD + v], acc);
  h1[(r0 + rl) * HD + v] = fmaxf(acc, 0.f);
}

// ---------------- L2 GEMM (h2 = relu(h1@W2+b2)) in parallel with mask-bilinear T = m1@E ----
// grid 256: blocks 0..127 = L2 role, 128..255 = BIL role. block 256 threads,
// each thread owns columns (tid, tid+256) over an 8-row tile. h1 tile staged
// transposed in LDS ([u][8 rows]) so each u-iter is 2 broadcast float4 reads + 16 FMA.
__global__ __launch_bounds__(256) void k_l2bil(const float* __restrict__ h1,
    const float* __restrict__ W2, const float* __restrict__ b2,
    const float* __restrict__ E, float* __restrict__ h2, float* __restrict__ T) {
  __shared__ __align__(16) float tile[HD * 8];   // 16 KB
  int bid = blockIdx.x;
  int bil = bid >> 7;                    // 0: L2, 1: bilinear
  int r0 = (bid & 127) << 3;
  int tid = threadIdx.x;
  const float* src = h1 + r0 * HD;
  if (!bil) {
    for (int idx = tid; idx < 4096; idx += 256) {
      int r = idx >> 9, u = idx & 511;
      tile[u * 8 + r] = src[r * HD + u];
    }
  } else {
    for (int idx = tid; idx < 4096; idx += 256) {
      int r = idx >> 9, u = idx & 511;
      tile[u * 8 + r] = (src[r * HD + u] > 0.f) ? 1.f : 0.f;   // m1 as 0/1 float
    }
  }
  __syncthreads();
  const float* __restrict__ M = bil ? E : W2;
  int v0 = tid, v1 = tid + 256;
  float a0[8] = {0.f, 0.f, 0.f, 0.f, 0.f, 0.f, 0.f, 0.f};
  float a1[8] = {0.f, 0.f, 0.f, 0.f, 0.f, 0.f, 0.f, 0.f};
#pragma unroll 4
  for (int u = 0; u < HD; ++u) {
    const float4* tp = (const float4*)(tile + u * 8);
    float4 p = tp[0];
    float4 q = tp[1];
    float w0 = M[u * HD + v0];
    float w1 = M[u * HD + v1];
    a0[0] = fmaf(p.x, w0, a0[0]);
    a0[1] = fmaf(p.y, w0, a0[1]);
    a0[2] = fmaf(p.z, w0, a0[2]);
    a0[3] = fmaf(p.w, w0, a0[3]);
    a0[4] = fmaf(q.x, w0, a0[4]);
    a0[5] = fmaf(q.y, w0, a0[5]);
    a0[6] = fmaf(q.z, w0, a0[6]);
    a0[7] = fmaf(q.w, w0, a0[7]);
    a1[0] = fmaf(p.x, w1, a1[0]);
    a1[1] = fmaf(p.y, w1, a1[1]);
    a1[2] = fmaf(p.z, w1, a1[2]);
    a1[3] = fmaf(p.w, w1, a1[3]);
    a1[4] = fmaf(q.x, w1, a1[4]);
    a1[5] = fmaf(q.y, w1, a1[5]);
    a1[6] = fmaf(q.z, w1, a1[6]);
    a1[7] = fmaf(q.w, w1, a1[7]);
  }
  if (!bil) {
    float bb0 = b2[v0], bb1 = b2[v1];
#pragma unroll
    for (int r = 0; r < 8; ++r) {
      h2[(r0 + r) * HD + v0] = fmaxf(a0[r] + bb0, 0.f);
      h2[(r0 + r) * HD + v1] = fmaxf(a1[r] + bb1, 0.f);
    }
  } else {
#pragma unroll
    for (int r = 0; r < 8; ++r) {
      T[(r0 + r) * HD + v0] = a0[r];
      T[(r0 + r) * HD + v1] = a1[r];
    }
  }
}

// ---------------- L3: y = h2@W3+b3, fused m2-gated trace + logdet update ----------------
// grid 256, block 256 = 4 rows x 64 cols (wave-aligned: lane == output dim j).
__global__ __launch_bounds__(256) void k_l3(const float* __restrict__ h2,
    const float* __restrict__ W3, const float* __restrict__ b3,
    float* __restrict__ yB, const float* __restrict__ yA,
    const float* __restrict__ T, float* __restrict__ logdet,
    float dt, float dtH, int do_trace) {
  __shared__ float ht[4 * HD];           // 8 KB
  int r0 = blockIdx.x << 2;
  int tid = threadIdx.x;
  for (int idx = tid; idx < 2048; idx += 256) ht[idx] = h2[r0 * HD + idx];
  __syncthreads();
  int rl = tid >> 6, j = tid & 63;
  int row = r0 + rl;
  const float* hrow = ht + rl * HD;
  float acc = b3[j];
#pragma unroll 4
  for (int v = 0; v < HD; ++v) acc = fmaf(hrow[v], W3[v * DD + j], acc);
  yB[row * DD + j] = acc;
  if (do_trace) {
    float d = acc - yA[row * DD + j];    // part2: (y_new - y_old)
    float g = 0.f;                        // m2-gated column sums of T
#pragma unroll
    for (int k = 0; k < 8; ++k) {
      int v = (k << 6) + j;
      g += (hrow[v] > 0.f) ? T[row * HD + v] : 0.f;
    }
    float val = fmaf(d, dtH, g * dt);
#pragma unroll
    for (int off = 32; off > 0; off >>= 1) val += __shfl_down(val, off);
    if (j == 0) logdet[row] -= val;      // single writer per row, stream-ordered
  }
}

// ---------------- pack outputs ----------------
__global__ __launch_bounds__(256) void k_out(const float* __restrict__ z,
    const float* __restrict__ logdet, float* __restrict__ out) {
  int i = blockIdx.x * 256 + threadIdx.x;     // 260*256 = 66560 exactly
  if (i < NB * DD) out[i] = z[i];
  else out[i] = logdet[i - NB * DD];
}

extern "C" void kernel_launch(void* const* d_in, const int* in_sizes, int n_in,
                              void* d_out, int out_size, void* d_ws, size_t ws_size,
                              hipStream_t stream) {
  const float* x  = (const float*)d_in[0];
  const float* W1 = (const float*)d_in[1];
  const float* b1 = (const float*)d_in[2];
  const float* W2 = (const float*)d_in[3];
  const float* b2 = (const float*)d_in[4];
  const float* W3 = (const float*)d_in[5];
  const float* b3 = (const float*)d_in[6];
  float* out = (float*)d_out;

  float* ws = (float*)d_ws;
  float* E   = ws;                       // 512*512
  float* h1  = E + HD * HD;              // 1024*512
  float* h2  = h1 + NB * HD;             // 1024*512
  float* T   = h2 + NB * HD;             // 1024*512
  float* zb0 = T + NB * HD;              // 1024*64
  float* zb1 = zb0 + NB * DD;
  float* y0  = zb1 + NB * DD;
  float* y1  = y0 + NB * DD;
  float* logdet = y1 + NB * DD;          // 1024   (total ~8.4 MB)

  float* zs[2] = {zb0, zb1};
  float* ys[2] = {y0, y1};

  // E + logdet init
  k_prep<<<512, 512, 0, stream>>>(W1, W2, W3, E, logdet);

  // forward at z_0 = x (dt=0 => zb0 becomes a copy of x; ya=x is just a finite dummy)
  k_l1<<<2048, 256, 0, stream>>>(x, zb0, x, 0.f, W1, b1, h1);
  k_l2bil<<<128, 256, 0, stream>>>(h1, W2, b2, E, h2, T);   // L2 role only
  k_l3<<<256, 256, 0, stream>>>(h2, W3, b3, y0, y0, T, logdet, 0.f, 0.f, 0);

  // replicate fp32 linspace timesteps
  double td[10];
  for (int i = 0; i < 10; ++i) td[i] = (double)i / 9.0;

  for (int t = 0; t < 9; ++t) {
    float dt  = (float)td[t + 1] - (float)td[t];
    float dtH = dt / 1e-5f;
    k_l1<<<2048, 256, 0, stream>>>(zs[t & 1], zs[(t + 1) & 1], ys[t & 1], dt,
                                   W1, b1, h1);
    k_l2bil<<<256, 256, 0, stream>>>(h1, W2, b2, E, h2, T);
    k_l3<<<256, 256, 0, stream>>>(h2, W3, b3, ys[(t + 1) & 1], ys[t & 1], T,
                                  logdet, dt, dtH, 1);
  }

  k_out<<<260, 256, 0, stream>>>(zs[1], logdet, out);
}

// Round 3
// 476.076 us; speedup vs baseline: 1.3787x; 1.3787x over previous
//
#include <hip/hip_runtime.h>

// NeuralODEFlow, restructured:
//   trace = [sum_j (y_new_j - y_old_j)]*dt/H + (m1^T E m2)*dt   (piecewise-linear MLP)
//   E[u,v] = W2[u,v] * (W3@W1)[v,u]  precomputed once.
// Round-3 fix: latency-bound GEMMs -> software-pipelined register prefetch
// (8-deep), fused z-update+L1+GEMM per role, 512-thread blocks.

#define HD 512
#define DD 64
#define NB 1024

// ---------------- E precompute + logdet zero ----------------
__global__ __launch_bounds__(512) void k_prep(const float* __restrict__ W1,
    const float* __restrict__ W2, const float* __restrict__ W3,
    float* __restrict__ E, float* __restrict__ logdet) {
  int v = blockIdx.x;       // 0..511
  int u = threadIdx.x;      // 0..511
  if (v < 2) logdet[v * 512 + u] = 0.f;
  float s = 0.f;
#pragma unroll 8
  for (int j = 0; j < DD; ++j)
    s = fmaf(W3[v * DD + j], W1[j * HD + u], s);
  E[u * HD + v] = W2[u * HD + v] * s;
}

// ---------------- fused step kernel A ----------------
// grid 256 x 512 threads. blocks 0..127: GEMM role (h2), 128..255: bilinear (T).
// Each block: 8 rows. z_new = z + y_old*dt; h1 = relu(z_new@W1+b1) kept in LDS
// (transposed [v][8]); then 512-K GEMM vs W2 (->h2) or E (->T) with 8-deep
// register prefetch of the streamed matrix column.
__global__ __launch_bounds__(512) void k_step_a(
    const float* __restrict__ zin, float* __restrict__ zout,
    const float* __restrict__ ya, float dt,
    const float* __restrict__ W1, const float* __restrict__ b1,
    const float* __restrict__ W2, const float* __restrict__ b2,
    const float* __restrict__ E,
    float* __restrict__ h2, float* __restrict__ T) {
  __shared__ __align__(16) float tile[HD * 8];   // 16 KB, h1^T or mask^T
  __shared__ __align__(16) float zt[8 * DD];     // 2 KB
  int bid = blockIdx.x;
  int bil = bid >> 7;
  int r0 = (bid & 127) << 3;
  int tid = threadIdx.x;                          // 0..511
  int v = tid;

  // z-update: one element per thread (8 rows x 64 dims = 512)
  {
    float zv = fmaf(ya[r0 * DD + tid], dt, zin[r0 * DD + tid]);
    zt[tid] = zv;
    if (!bil) zout[r0 * DD + tid] = zv;
  }
  __syncthreads();

  // h1 for 8 rows at column v (K = 64), 4-deep W1 prefetch
  float hv[8];
  {
    float acc[8];
    float bb = b1[v];
#pragma unroll
    for (int r = 0; r < 8; ++r) acc[r] = bb;
    float wn[4];
#pragma unroll
    for (int i = 0; i < 4; ++i) wn[i] = W1[i * HD + v];
    for (int k0 = 0; k0 < DD; k0 += 4) {
      float wc[4];
#pragma unroll
      for (int i = 0; i < 4; ++i) wc[i] = wn[i];
      if (k0 + 4 < DD) {
        const float* Wn = W1 + (k0 + 4) * HD + v;
#pragma unroll
        for (int i = 0; i < 4; ++i) wn[i] = Wn[i * HD];
      }
      float4 z4[8];
#pragma unroll
      for (int r = 0; r < 8; ++r)
        z4[r] = *(const float4*)(zt + r * DD + k0);
#pragma unroll
      for (int r = 0; r < 8; ++r) {
        acc[r] = fmaf(z4[r].x, wc[0], acc[r]);
        acc[r] = fmaf(z4[r].y, wc[1], acc[r]);
        acc[r] = fmaf(z4[r].z, wc[2], acc[r]);
        acc[r] = fmaf(z4[r].w, wc[3], acc[r]);
      }
    }
    if (!bil) {
#pragma unroll
      for (int r = 0; r < 8; ++r) hv[r] = fmaxf(acc[r], 0.f);
    } else {
#pragma unroll
      for (int r = 0; r < 8; ++r) hv[r] = (acc[r] > 0.f) ? 1.f : 0.f;
    }
  }
  // write transposed tile (two b128 stores)
  *(float4*)(tile + v * 8)     = make_float4(hv[0], hv[1], hv[2], hv[3]);
  *(float4*)(tile + v * 8 + 4) = make_float4(hv[4], hv[5], hv[6], hv[7]);
  __syncthreads();

  // 512-K GEMM: out[r][v] = sum_u tile[u][r] * M[u][v], 8-deep M prefetch
  const float* __restrict__ M = bil ? E : W2;
  float a[8];
#pragma unroll
  for (int r = 0; r < 8; ++r) a[r] = 0.f;
  float wn[8];
#pragma unroll
  for (int i = 0; i < 8; ++i) wn[i] = M[i * HD + v];
  for (int u0 = 0; u0 < HD; u0 += 8) {
    float wc[8];
#pragma unroll
    for (int i = 0; i < 8; ++i) wc[i] = wn[i];
    if (u0 + 8 < HD) {
      const float* Mn = M + (u0 + 8) * HD + v;
#pragma unroll
      for (int i = 0; i < 8; ++i) wn[i] = Mn[i * HD];
    }
#pragma unroll
    for (int i = 0; i < 8; ++i) {
      const float4* tp = (const float4*)(tile + (u0 + i) * 8);
      float4 p = tp[0];
      float4 q = tp[1];
      float w = wc[i];
      a[0] = fmaf(p.x, w, a[0]);
      a[1] = fmaf(p.y, w, a[1]);
      a[2] = fmaf(p.z, w, a[2]);
      a[3] = fmaf(p.w, w, a[3]);
      a[4] = fmaf(q.x, w, a[4]);
      a[5] = fmaf(q.y, w, a[5]);
      a[6] = fmaf(q.z, w, a[6]);
      a[7] = fmaf(q.w, w, a[7]);
    }
  }
  if (!bil) {
    float bb = b2[v];
#pragma unroll
    for (int r = 0; r < 8; ++r)
      h2[(r0 + r) * HD + v] = fmaxf(a[r] + bb, 0.f);
  } else {
#pragma unroll
    for (int r = 0; r < 8; ++r)
      T[(r0 + r) * HD + v] = a[r];
  }
}

// ---------------- step kernel B: y = h2@W3+b3, trace, logdet ----------------
// grid 256 x 256 threads = 4 rows x 64 cols. 8-deep W3 prefetch, 8 partial accs.
__global__ __launch_bounds__(256) void k_step_b(
    const float* __restrict__ h2, const float* __restrict__ W3,
    const float* __restrict__ b3, float* __restrict__ yB,
    const float* __restrict__ yA, const float* __restrict__ T,
    float* __restrict__ logdet, float dt, float dtH, int do_trace) {
  __shared__ __align__(16) float ht[4 * HD];     // 8 KB
  int r0 = blockIdx.x << 2;
  int tid = threadIdx.x;
  for (int idx = tid; idx < 512; idx += 256)
    *(float4*)(ht + idx * 4) = *(const float4*)(h2 + r0 * HD + idx * 4);
  __syncthreads();
  int rl = tid >> 6, j = tid & 63;
  int row = r0 + rl;
  const float* hrow = ht + rl * HD;
  float acc[8];
#pragma unroll
  for (int i = 0; i < 8; ++i) acc[i] = 0.f;
  float wn[8];
#pragma unroll
  for (int i = 0; i < 8; ++i) wn[i] = W3[i * DD + j];
  for (int v0 = 0; v0 < HD; v0 += 8) {
    float wc[8];
#pragma unroll
    for (int i = 0; i < 8; ++i) wc[i] = wn[i];
    if (v0 + 8 < HD) {
      const float* Wn = W3 + (v0 + 8) * DD + j;
#pragma unroll
      for (int i = 0; i < 8; ++i) wn[i] = Wn[i * DD];
    }
#pragma unroll
    for (int i = 0; i < 8; ++i)
      acc[i] = fmaf(hrow[v0 + i], wc[i], acc[i]);
  }
  float y = b3[j] + ((acc[0] + acc[1]) + (acc[2] + acc[3])) +
            ((acc[4] + acc[5]) + (acc[6] + acc[7]));
  yB[row * DD + j] = y;
  if (do_trace) {
    float d = y - yA[row * DD + j];
    float g = 0.f;
#pragma unroll
    for (int k = 0; k < 8; ++k) {
      int vv = (k << 6) + j;
      float tv = T[row * HD + vv];
      g += (hrow[vv] > 0.f) ? tv : 0.f;
    }
    float val = fmaf(d, dtH, g * dt);
#pragma unroll
    for (int off = 32; off > 0; off >>= 1) val += __shfl_down(val, off);
    if (j == 0) logdet[row] -= val;
  }
}

// ---------------- pack outputs ----------------
__global__ __launch_bounds__(256) void k_out(const float* __restrict__ z,
    const float* __restrict__ logdet, float* __restrict__ out) {
  int i = blockIdx.x * 256 + threadIdx.x;     // 260*256 = 66560 exactly
  if (i < NB * DD) out[i] = z[i];
  else out[i] = logdet[i - NB * DD];
}

extern "C" void kernel_launch(void* const* d_in, const int* in_sizes, int n_in,
                              void* d_out, int out_size, void* d_ws, size_t ws_size,
                              hipStream_t stream) {
  const float* x  = (const float*)d_in[0];
  const float* W1 = (const float*)d_in[1];
  const float* b1 = (const float*)d_in[2];
  const float* W2 = (const float*)d_in[3];
  const float* b2 = (const float*)d_in[4];
  const float* W3 = (const float*)d_in[5];
  const float* b3 = (const float*)d_in[6];
  float* out = (float*)d_out;

  float* ws = (float*)d_ws;
  float* E   = ws;                       // 512*512
  float* h2  = E + HD * HD;              // 1024*512
  float* T   = h2 + NB * HD;             // 1024*512
  float* zb0 = T + NB * HD;              // 1024*64
  float* zb1 = zb0 + NB * DD;
  float* y0  = zb1 + NB * DD;
  float* y1  = y0 + NB * DD;
  float* logdet = y1 + NB * DD;          // 1024   (total ~6.3 MB)

  float* zs[2] = {zb0, zb1};
  float* ys[2] = {y0, y1};

  k_prep<<<512, 512, 0, stream>>>(W1, W2, W3, E, logdet);

  // forward at z_0 = x (dt=0 => zb0 = x; ya=x is a finite dummy)
  k_step_a<<<256, 512, 0, stream>>>(x, zb0, x, 0.f, W1, b1, W2, b2, E, h2, T);
  k_step_b<<<256, 256, 0, stream>>>(h2, W3, b3, y0, y0, T, logdet, 0.f, 0.f, 0);

  double td[10];
  for (int i = 0; i < 10; ++i) td[i] = (double)i / 9.0;

  for (int t = 0; t < 9; ++t) {
    float dt  = (float)td[t + 1] - (float)td[t];
    float dtH = dt / 1e-5f;
    k_step_a<<<256, 512, 0, stream>>>(zs[t & 1], zs[(t + 1) & 1], ys[t & 1], dt,
                                      W1, b1, W2, b2, E, h2, T);
    k_step_b<<<256, 256, 0, stream>>>(h2, W3, b3, ys[(t + 1) & 1], ys[t & 1], T,
                                      logdet, dt, dtH, 1);
  }

  k_out<<<260, 256, 0, stream>>>(zs[1], logdet, out);
}

// Round 5
// 398.953 us; speedup vs baseline: 1.6452x; 1.1933x over previous
//
#include <hip/hip_runtime.h>

// NeuralODEFlow:
//   trace = [sum_j (y_new_j - y_old_j)]*dt/H + (m1^T E m2)*dt   (piecewise-linear MLP)
//   E[u,v] = W2[u,v] * (W3@W1)[v,u]  precomputed once.
// Round-4: kill LDS-broadcast boundedness. Phase-2 GEMM: R=4 x C=4, K-halved
// across thread-halves (1 b128 + 1 float4 per 16 FMA), 8-deep prefetch rings.
// Phase-1 rebuilt with transposed z-tile (1 b128 per 8 FMA). k_step_b quadified.

#define HD 512
#define DD 64
#define NB 1024

__device__ __forceinline__ void fma16(const float4 t, const float4 m, float* a) {
  a[0]  = fmaf(t.x, m.x, a[0]);  a[1]  = fmaf(t.x, m.y, a[1]);
  a[2]  = fmaf(t.x, m.z, a[2]);  a[3]  = fmaf(t.x, m.w, a[3]);
  a[4]  = fmaf(t.y, m.x, a[4]);  a[5]  = fmaf(t.y, m.y, a[5]);
  a[6]  = fmaf(t.y, m.z, a[6]);  a[7]  = fmaf(t.y, m.w, a[7]);
  a[8]  = fmaf(t.z, m.x, a[8]);  a[9]  = fmaf(t.z, m.y, a[9]);
  a[10] = fmaf(t.z, m.z, a[10]); a[11] = fmaf(t.z, m.w, a[11]);
  a[12] = fmaf(t.w, m.x, a[12]); a[13] = fmaf(t.w, m.y, a[13]);
  a[14] = fmaf(t.w, m.z, a[14]); a[15] = fmaf(t.w, m.w, a[15]);
}

__device__ __forceinline__ void fma8(const float4 z, const float2 w, float* a) {
  a[0] = fmaf(z.x, w.x, a[0]); a[1] = fmaf(z.x, w.y, a[1]);
  a[2] = fmaf(z.y, w.x, a[2]); a[3] = fmaf(z.y, w.y, a[3]);
  a[4] = fmaf(z.z, w.x, a[4]); a[5] = fmaf(z.z, w.y, a[5]);
  a[6] = fmaf(z.w, w.x, a[6]); a[7] = fmaf(z.w, w.y, a[7]);
}

// ---------------- E precompute + logdet zero ----------------
// block = u (512), thread = v (512): E write coalesced; W3 row reads L1-cached.
__global__ __launch_bounds__(512) void k_prep(const float* __restrict__ W1,
    const float* __restrict__ W2, const float* __restrict__ W3,
    float* __restrict__ E, float* __restrict__ logdet) {
  int u = blockIdx.x;
  int v = threadIdx.x;
  if (u < 2) logdet[u * HD + v] = 0.f;
  float s = 0.f;
#pragma unroll 8
  for (int j = 0; j < DD; ++j)
    s = fmaf(W3[v * DD + j], W1[j * HD + u], s);
  E[u * HD + v] = W2[u * HD + v] * s;
}

// ---------------- fused step kernel A ----------------
// grid 256 x 512. blocks 0..127: h2 role, 128..255: bilinear (T). 8 rows/block.
__global__ __launch_bounds__(512) void k_step_a(
    const float* __restrict__ zin, float* __restrict__ zout,
    const float* __restrict__ ya, float dt,
    const float* __restrict__ W1, const float* __restrict__ b1,
    const float* __restrict__ W2, const float* __restrict__ b2,
    const float* __restrict__ E,
    float* __restrict__ h2, float* __restrict__ T) {
  __shared__ __align__(16) float ztT[DD * 8];     // z transposed [k][r], 2 KB
  __shared__ __align__(16) float tile[HD * 8];    // [u][r] h1 or mask, 16 KB
  __shared__ __align__(16) float scr[256 * 16];   // K-half partials, 16 KB
  int bid = blockIdx.x;
  int bil = bid >> 7;
  int r0 = (bid & 127) << 3;
  int tid = threadIdx.x;

  // phase 0: Euler update (dt=0 on init pass)
  {
    float zv = fmaf(ya[r0 * DD + tid], dt, zin[r0 * DD + tid]);
    ztT[(tid & 63) * 8 + (tid >> 6)] = zv;
    if (!bil) zout[r0 * DD + tid] = zv;
  }
  __syncthreads();

  // phase 1: h1 = relu(z_new@W1+b1) (or mask), K=64, -> tile[u][r]
  {
    int rh = tid >> 8;            // row half: rows rh*4..rh*4+3
    int v0 = (tid & 255) * 2;     // 2 columns
    const float* zp = ztT + rh * 4;
    float acc[8];                  // [rr][c]
    float2 bb = *(const float2*)(b1 + v0);
#pragma unroll
    for (int rr = 0; rr < 4; ++rr) { acc[rr * 2] = bb.x; acc[rr * 2 + 1] = bb.y; }
    float2 w0 = *(const float2*)(W1 + 0 * HD + v0);
    float2 w1 = *(const float2*)(W1 + 1 * HD + v0);
    float2 w2 = *(const float2*)(W1 + 2 * HD + v0);
    float2 w3 = *(const float2*)(W1 + 3 * HD + v0);
    float2 w4 = *(const float2*)(W1 + 4 * HD + v0);
    float2 w5 = *(const float2*)(W1 + 5 * HD + v0);
    float2 w6 = *(const float2*)(W1 + 6 * HD + v0);
    float2 w7 = *(const float2*)(W1 + 7 * HD + v0);
    float4 z0 = *(const float4*)(zp + 0 * 8);
    float4 z1 = *(const float4*)(zp + 1 * 8);
    float4 z2 = *(const float4*)(zp + 2 * 8);
    float4 z3 = *(const float4*)(zp + 3 * 8);
    float4 z4 = *(const float4*)(zp + 4 * 8);
    float4 z5 = *(const float4*)(zp + 5 * 8);
    float4 z6 = *(const float4*)(zp + 6 * 8);
    float4 z7 = *(const float4*)(zp + 7 * 8);
#define STEP1(ws, zs, koff)                                                  \
    fma8(zs, ws, acc);                                                       \
    if (k8 != 7) {                                                           \
      ws = *(const float2*)(W1 + (k8 * 8 + 8 + koff) * HD + v0);             \
      zs = *(const float4*)(zp + (k8 * 8 + 8 + koff) * 8);                   \
    }
    for (int k8 = 0; k8 < 8; ++k8) {
      STEP1(w0, z0, 0) STEP1(w1, z1, 1) STEP1(w2, z2, 2) STEP1(w3, z3, 3)
      STEP1(w4, z4, 4) STEP1(w5, z5, 5) STEP1(w6, z6, 6) STEP1(w7, z7, 7)
    }
#undef STEP1
    if (!bil) {
#pragma unroll
      for (int i = 0; i < 8; ++i) acc[i] = fmaxf(acc[i], 0.f);
    } else {
#pragma unroll
      for (int i = 0; i < 8; ++i) acc[i] = (acc[i] > 0.f) ? 1.f : 0.f;
    }
    *(float4*)(tile + (v0 + 0) * 8 + rh * 4) =
        make_float4(acc[0], acc[2], acc[4], acc[6]);
    *(float4*)(tile + (v0 + 1) * 8 + rh * 4) =
        make_float4(acc[1], acc[3], acc[5], acc[7]);
  }
  __syncthreads();

  // phase 2: 512-K GEMM, K split across thread-halves. R=4 x C=4.
  {
    int kh = tid >> 8;            // K-half
    int rg = (tid >> 7) & 1;      // rowgroup (4 rows)
    int colg = tid & 127;
    int v0 = colg << 2;
    const float* __restrict__ M = bil ? E : W2;
    const float* Mp = M + (kh * 256) * HD + v0;
    const float* tp = tile + (kh * 256) * 8 + rg * 4;
    float a[16];
#pragma unroll
    for (int i = 0; i < 16; ++i) a[i] = 0.f;
    float4 m0 = *(const float4*)(Mp + 0 * HD);
    float4 m1 = *(const float4*)(Mp + 1 * HD);
    float4 m2 = *(const float4*)(Mp + 2 * HD);
    float4 m3 = *(const float4*)(Mp + 3 * HD);
    float4 m4 = *(const float4*)(Mp + 4 * HD);
    float4 m5 = *(const float4*)(Mp + 5 * HD);
    float4 m6 = *(const float4*)(Mp + 6 * HD);
    float4 m7 = *(const float4*)(Mp + 7 * HD);
    float4 t0 = *(const float4*)(tp + 0 * 8);
    float4 t1 = *(const float4*)(tp + 1 * 8);
    float4 t2 = *(const float4*)(tp + 2 * 8);
    float4 t3 = *(const float4*)(tp + 3 * 8);
    float4 t4 = *(const float4*)(tp + 4 * 8);
    float4 t5 = *(const float4*)(tp + 5 * 8);
    float4 t6 = *(const float4*)(tp + 6 * 8);
    float4 t7 = *(const float4*)(tp + 7 * 8);
#define STEP2(ms, ts, uoff)                                                  \
    fma16(ts, ms, a);                                                        \
    if (u8 != 31) {                                                          \
      ms = *(const float4*)(Mp + (u8 * 8 + 8 + uoff) * HD);                  \
      ts = *(const float4*)(tp + (u8 * 8 + 8 + uoff) * 8);                   \
    }
    for (int u8 = 0; u8 < 32; ++u8) {
      STEP2(m0, t0, 0) STEP2(m1, t1, 1) STEP2(m2, t2, 2) STEP2(m3, t3, 3)
      STEP2(m4, t4, 4) STEP2(m5, t5, 5) STEP2(m6, t6, 6) STEP2(m7, t7, 7)
    }
#undef STEP2
    int slot = ((rg << 7) | colg) << 4;
    if (kh) {
#pragma unroll
      for (int rr = 0; rr < 4; ++rr)
        *(float4*)(scr + slot + rr * 4) =
            make_float4(a[rr * 4], a[rr * 4 + 1], a[rr * 4 + 2], a[rr * 4 + 3]);
    }
    __syncthreads();
    if (!kh) {
      if (!bil) {
        float4 bb = *(const float4*)(b2 + v0);
#pragma unroll
        for (int rr = 0; rr < 4; ++rr) {
          float4 s = *(const float4*)(scr + slot + rr * 4);
          float4 o;
          o.x = fmaxf(a[rr * 4 + 0] + s.x + bb.x, 0.f);
          o.y = fmaxf(a[rr * 4 + 1] + s.y + bb.y, 0.f);
          o.z = fmaxf(a[rr * 4 + 2] + s.z + bb.z, 0.f);
          o.w = fmaxf(a[rr * 4 + 3] + s.w + bb.w, 0.f);
          *(float4*)(h2 + (r0 + rg * 4 + rr) * HD + v0) = o;
        }
      } else {
#pragma unroll
        for (int rr = 0; rr < 4; ++rr) {
          float4 s = *(const float4*)(scr + slot + rr * 4);
          float4 o;
          o.x = a[rr * 4 + 0] + s.x;
          o.y = a[rr * 4 + 1] + s.y;
          o.z = a[rr * 4 + 2] + s.z;
          o.w = a[rr * 4 + 3] + s.w;
          *(float4*)(T + (r0 + rg * 4 + rr) * HD + v0) = o;
        }
      }
    }
  }
}

// ---------------- step kernel B: y = h2@W3+b3, trace, logdet ----------------
// grid 256 x 256 = 4 rows x 64 cols. b128 quad reads, 4-deep W3 ring.
__global__ __launch_bounds__(256) void k_step_b(
    const float* __restrict__ h2, const float* __restrict__ W3,
    const float* __restrict__ b3, float* __restrict__ yB,
    const float* __restrict__ yA, const float* __restrict__ T,
    float* __restrict__ logdet, float dt, float dtH, int do_trace) {
  __shared__ __align__(16) float ht[4 * HD];     // 8 KB
  int r0 = blockIdx.x << 2;
  int tid = threadIdx.x;
  for (int idx = tid; idx < 512; idx += 256)
    ((float4*)ht)[idx] = ((const float4*)(h2 + r0 * HD))[idx];
  __syncthreads();
  int rl = tid >> 6, j = tid & 63;
  int row = r0 + rl;
  const float* hrow = ht + rl * HD;
  float a0 = 0.f, a1 = 0.f, a2 = 0.f, a3 = 0.f;
  float4 w0, w1, w2, w3;
  float4 h0, h1v, h2v, h3;
#define LDW(ws, q) ws.x = W3[((q) * 4 + 0) * DD + j];                        \
                   ws.y = W3[((q) * 4 + 1) * DD + j];                        \
                   ws.z = W3[((q) * 4 + 2) * DD + j];                        \
                   ws.w = W3[((q) * 4 + 3) * DD + j];
  LDW(w0, 0) LDW(w1, 1) LDW(w2, 2) LDW(w3, 3)
  h0  = *(const float4*)(hrow + 0);
  h1v = *(const float4*)(hrow + 4);
  h2v = *(const float4*)(hrow + 8);
  h3  = *(const float4*)(hrow + 12);
#define STEPB(hs, ws, qoff)                                                  \
  a0 = fmaf(hs.x, ws.x, a0); a1 = fmaf(hs.y, ws.y, a1);                      \
  a2 = fmaf(hs.z, ws.z, a2); a3 = fmaf(hs.w, ws.w, a3);                      \
  if (q4 != 31) {                                                            \
    LDW(ws, q4 * 4 + 4 + qoff)                                               \
    hs = *(const float4*)(hrow + (q4 * 4 + 4 + qoff) * 4);                   \
  }
  for (int q4 = 0; q4 < 32; ++q4) {
    STEPB(h0, w0, 0) STEPB(h1v, w1, 1) STEPB(h2v, w2, 2) STEPB(h3, w3, 3)
  }
#undef STEPB
#undef LDW
  float y = b3[j] + ((a0 + a1) + (a2 + a3));
  yB[row * DD + j] = y;
  if (do_trace) {
    float d = y - yA[row * DD + j];
    float g = 0.f;
#pragma unroll
    for (int k = 0; k < 8; ++k) {
      int vv = (k << 6) + j;
      float tv = T[row * HD + vv];
      g += (hrow[vv] > 0.f) ? tv : 0.f;
    }
    float val = fmaf(d, dtH, g * dt);
#pragma unroll
    for (int off = 32; off > 0; off >>= 1) val += __shfl_down(val, off);
    if (j == 0) logdet[row] -= val;
  }
}

// ---------------- pack outputs ----------------
__global__ __launch_bounds__(256) void k_out(const float* __restrict__ z,
    const float* __restrict__ logdet, float* __restrict__ out) {
  int i = blockIdx.x * 256 + threadIdx.x;     // 260*256 = 66560 exactly
  if (i < NB * DD) out[i] = z[i];
  else out[i] = logdet[i - NB * DD];
}

extern "C" void kernel_launch(void* const* d_in, const int* in_sizes, int n_in,
                              void* d_out, int out_size, void* d_ws, size_t ws_size,
                              hipStream_t stream) {
  const float* x  = (const float*)d_in[0];
  const float* W1 = (const float*)d_in[1];
  const float* b1 = (const float*)d_in[2];
  const float* W2 = (const float*)d_in[3];
  const float* b2 = (const float*)d_in[4];
  const float* W3 = (const float*)d_in[5];
  const float* b3 = (const float*)d_in[6];
  float* out = (float*)d_out;

  float* ws = (float*)d_ws;
  float* E   = ws;                       // 512*512
  float* h2  = E + HD * HD;              // 1024*512
  float* T   = h2 + NB * HD;             // 1024*512
  float* zb0 = T + NB * HD;              // 1024*64
  float* zb1 = zb0 + NB * DD;
  float* y0  = zb1 + NB * DD;
  float* y1  = y0 + NB * DD;
  float* logdet = y1 + NB * DD;          // 1024

  float* zs[2] = {zb0, zb1};
  float* ys[2] = {y0, y1};

  k_prep<<<512, 512, 0, stream>>>(W1, W2, W3, E, logdet);

  // forward at z_0 = x (dt=0 => zb0 = x)
  k_step_a<<<256, 512, 0, stream>>>(x, zb0, x, 0.f, W1, b1, W2, b2, E, h2, T);
  k_step_b<<<256, 256, 0, stream>>>(h2, W3, b3, y0, y0, T, logdet, 0.f, 0.f, 0);

  double td[10];
  for (int i = 0; i < 10; ++i) td[i] = (double)i / 9.0;

  for (int t = 0; t < 9; ++t) {
    float dt  = (float)td[t + 1] - (float)td[t];
    float dtH = dt / 1e-5f;
    k_step_a<<<256, 512, 0, stream>>>(zs[t & 1], zs[(t + 1) & 1], ys[t & 1], dt,
                                      W1, b1, W2, b2, E, h2, T);
    k_step_b<<<256, 256, 0, stream>>>(h2, W3, b3, ys[(t + 1) & 1], ys[t & 1], T,
                                      logdet, dt, dtH, 1);
  }

  k_out<<<260, 256, 0, stream>>>(zs[1], logdet, out);
}

// Round 7
// 286.966 us; speedup vs baseline: 2.2872x; 1.3902x over previous
//
#include <hip/hip_runtime.h>

// NeuralODEFlow via piecewise-linear trace decomposition + MFMA:
//   trace = [sum_j (y_new_j - y_old_j)]*dt/H + (m1^T E m2)*dt
//   E[u,v] = W2[u,v] * (W3@W1)[v,u]  (precomputed, bf16)
// GEMMs on matrix cores (16x16x32 bf16). y-path (h1,h2) uses 4-product
// hi/lo bf16 split (err ~2^-17, safe under the 1e5 part2 amplification);
// T-path single bf16. W1/W2/E pre-packed in B-fragment order by k_prep.

#define HD 512
#define DD 64
#define NB 1024

typedef __attribute__((ext_vector_type(8))) short short8;   // 8 bf16
typedef __attribute__((ext_vector_type(4))) float f32x4;

__device__ __forceinline__ unsigned short bf16_rn(float x) {
  unsigned int u = __float_as_uint(x);
  u += 0x7FFFu + ((u >> 16) & 1u);
  return (unsigned short)(u >> 16);
}
__device__ __forceinline__ float bf16_f(unsigned short h) {
  return __uint_as_float(((unsigned int)h) << 16);
}
#define MFMA(a, b, c) __builtin_amdgcn_mfma_f32_16x16x32_bf16(a, b, c, 0, 0, 0)

// ---------------- k_prep: logdet zero; pack W1,W2 (hi/lo) and E (bf16) ----------------
// grid 512 (k), block 512 (n). Fragment order: element (k,n) -> chunk
// (kc=k/32, nc=n/16), lane = ((k>>3)&3)*16 + (n&15), sub j = k&7;
// off = ((kc*32+nc)*64 + lane)*8 + j  => each lane's 8 bf16 contiguous.
__global__ __launch_bounds__(512) void k_prep(const float* __restrict__ W1,
    const float* __restrict__ W2, const float* __restrict__ W3,
    short* __restrict__ W1h, short* __restrict__ W1l,
    short* __restrict__ W2h, short* __restrict__ W2l,
    short* __restrict__ Ep, float* __restrict__ logdet) {
  int k = blockIdx.x;
  int n = threadIdx.x;
  if (k < 2) logdet[k * HD + n] = 0.f;
  int kg = (k >> 3) & 3, j = k & 7;
  int nc = n >> 4, nl = n & 15;
  int lane = kg * 16 + nl;
  long off = ((long)((k >> 5) * 32 + nc) * 64 + lane) * 8 + j;
  float w2 = W2[k * HD + n];
  unsigned short h = bf16_rn(w2);
  W2h[off] = (short)h;
  W2l[off] = (short)bf16_rn(w2 - bf16_f(h));
  float s = 0.f;
#pragma unroll 8
  for (int q = 0; q < DD; ++q)
    s = fmaf(W3[n * DD + q], W1[q * HD + k], s);   // K[v=n][u=k]
  Ep[off] = (short)bf16_rn(w2 * s);                // E[u=k][v=n]
  if (k < DD) {
    float w1 = W1[k * HD + n];
    long off1 = ((long)((k >> 5) * 32 + nc) * 64 + lane) * 8 + j;
    unsigned short h1b = bf16_rn(w1);
    W1h[off1] = (short)h1b;
    W1l[off1] = (short)bf16_rn(w1 - bf16_f(h1b));
  }
}

// ---------------- k_step: z-update + h1 (MFMA) + {h2, T} (MFMA) ----------------
// grid 256 = 64 row-groups (16 rows) x 4 col-slices (128 cols). 512 threads.
// LDS: z hi/lo [16][64+8] bf16; h1 hi/lo/mask [16][512+8] bf16 (pad keeps
// fragment ds_read_b128 at 2-way bank aliasing = free).
__global__ __launch_bounds__(512) void k_step(
    const float* __restrict__ zin, float* __restrict__ zout,
    const float* __restrict__ ya, float dt,
    const float* __restrict__ b1, const float* __restrict__ b2,
    const short* __restrict__ W1h, const short* __restrict__ W1l,
    const short* __restrict__ W2h, const short* __restrict__ W2l,
    const short* __restrict__ Ep,
    float* __restrict__ h2, float* __restrict__ Tt) {
  __shared__ __align__(16) short zh[16 * 72];
  __shared__ __align__(16) short zl[16 * 72];
  __shared__ __align__(16) short hh[16 * 520];
  __shared__ __align__(16) short hl[16 * 520];
  __shared__ __align__(16) short hm[16 * 520];
  int bid = blockIdx.x;
  int cs = bid & 3;            // col slice (128 cols)
  int r0 = (bid >> 2) << 4;    // 16-row group base
  int tid = threadIdx.x;
  int l = tid & 63;
  int w = tid >> 6;            // wave 0..7

  // ---- phase 0: Euler update, split z into bf16 hi/lo in LDS ----
  {
    int row = tid >> 5;
    int d0 = (tid & 31) * 2;
    float2 zi = *(const float2*)(zin + (r0 + row) * DD + d0);
    float2 yi = *(const float2*)(ya + (r0 + row) * DD + d0);
    float zx = fmaf(yi.x, dt, zi.x);
    float zy = fmaf(yi.y, dt, zi.y);
    if (cs == 0) *(float2*)(zout + (r0 + row) * DD + d0) = make_float2(zx, zy);
    unsigned short hx = bf16_rn(zx), hy = bf16_rn(zy);
    *(unsigned int*)(zh + row * 72 + d0) = (unsigned int)hx | ((unsigned int)hy << 16);
    unsigned short lx = bf16_rn(zx - bf16_f(hx)), ly = bf16_rn(zy - bf16_f(hy));
    *(unsigned int*)(zl + row * 72 + d0) = (unsigned int)lx | ((unsigned int)ly << 16);
  }
  __syncthreads();

  // ---- phase 1: h1 = relu(z@W1+b1), all 512 cols; wave w -> nc w*4..w*4+3 ----
  {
    int mrow = l & 15;
    int kg = l >> 4;
    short8 az0h = *(const short8*)(zh + mrow * 72 + kg * 8);
    short8 az0l = *(const short8*)(zl + mrow * 72 + kg * 8);
    short8 az1h = *(const short8*)(zh + mrow * 72 + 32 + kg * 8);
    short8 az1l = *(const short8*)(zl + mrow * 72 + 32 + kg * 8);
    for (int i = 0; i < 4; ++i) {
      int nc = w * 4 + i;
      f32x4 acc = {0.f, 0.f, 0.f, 0.f};
      short8 b0h = *(const short8*)(W1h + ((long)(nc) * 64 + l) * 8);
      short8 b0l = *(const short8*)(W1l + ((long)(nc) * 64 + l) * 8);
      short8 c1h = *(const short8*)(W1h + ((long)(32 + nc) * 64 + l) * 8);
      short8 c1l = *(const short8*)(W1l + ((long)(32 + nc) * 64 + l) * 8);
      acc = MFMA(az0h, b0h, acc); acc = MFMA(az0h, b0l, acc);
      acc = MFMA(az0l, b0h, acc); acc = MFMA(az0l, b0l, acc);
      acc = MFMA(az1h, c1h, acc); acc = MFMA(az1h, c1l, acc);
      acc = MFMA(az1l, c1h, acc); acc = MFMA(az1l, c1l, acc);
      int n = nc * 16 + (l & 15);
      float bb = b1[n];
#pragma unroll
      for (int reg = 0; reg < 4; ++reg) {
        float h = fmaxf(acc[reg] + bb, 0.f);
        int r = (l >> 4) * 4 + reg;
        unsigned short uh = bf16_rn(h);
        unsigned short ul = bf16_rn(h - bf16_f(uh));
        unsigned short um = (h > 0.f) ? 0x3F80u : 0u;
        int ph = __shfl_xor((int)uh, 1);
        int pl = __shfl_xor((int)ul, 1);
        int pm = __shfl_xor((int)um, 1);
        if ((l & 1) == 0) {   // n even: pack (n, n+1) into one b32 write
          int base = r * 520 + n;
          *(unsigned int*)(hh + base) = (unsigned int)uh | (((unsigned int)(unsigned short)ph) << 16);
          *(unsigned int*)(hl + base) = (unsigned int)ul | (((unsigned int)(unsigned short)pl) << 16);
          *(unsigned int*)(hm + base) = (unsigned int)um | (((unsigned int)(unsigned short)pm) << 16);
        }
      }
    }
  }
  __syncthreads();

  // ---- phase 2: h2 = relu(h1@W2+b2) [4-product split], T = m1@E [bf16] ----
  {
    int mrow = l & 15;
    int kg = l >> 4;
    int ncg = cs * 8 + w;            // global n-chunk for this wave
    int n = ncg * 16 + mrow;
    f32x4 aH = {0.f, 0.f, 0.f, 0.f};
    f32x4 aT = {0.f, 0.f, 0.f, 0.f};
#pragma unroll 4
    for (int kc = 0; kc < 16; ++kc) {
      short8 Ah = *(const short8*)(hh + mrow * 520 + kc * 32 + kg * 8);
      short8 Al = *(const short8*)(hl + mrow * 520 + kc * 32 + kg * 8);
      short8 Am = *(const short8*)(hm + mrow * 520 + kc * 32 + kg * 8);
      long boff = ((long)(kc * 32 + ncg) * 64 + l) * 8;
      short8 Bh = *(const short8*)(W2h + boff);
      short8 Bl = *(const short8*)(W2l + boff);
      short8 Be = *(const short8*)(Ep + boff);
      aH = MFMA(Ah, Bh, aH); aH = MFMA(Ah, Bl, aH);
      aH = MFMA(Al, Bh, aH); aH = MFMA(Al, Bl, aH);
      aT = MFMA(Am, Be, aT);
    }
    float bb2 = b2[n];
#pragma unroll
    for (int reg = 0; reg < 4; ++reg) {
      int r = kg * 4 + reg;
      h2[(r0 + r) * HD + n] = fmaxf(aH[reg] + bb2, 0.f);
      Tt[(r0 + r) * HD + n] = aT[reg];
    }
  }
}

// ---------------- k_step_b: y = h2@W3+b3 (fp32), trace, logdet ----------------
// grid 256 x 256 = 4 rows x 64 cols. Unchanged from the passing round-4 kernel.
__global__ __launch_bounds__(256) void k_step_b(
    const float* __restrict__ h2, const float* __restrict__ W3,
    const float* __restrict__ b3, float* __restrict__ yB,
    const float* __restrict__ yA, const float* __restrict__ T,
    float* __restrict__ logdet, float dt, float dtH, int do_trace) {
  __shared__ __align__(16) float ht[4 * HD];
  int r0 = blockIdx.x << 2;
  int tid = threadIdx.x;
  for (int idx = tid; idx < 512; idx += 256)
    ((float4*)ht)[idx] = ((const float4*)(h2 + r0 * HD))[idx];
  __syncthreads();
  int rl = tid >> 6, j = tid & 63;
  int row = r0 + rl;
  const float* hrow = ht + rl * HD;
  float a0 = 0.f, a1 = 0.f, a2 = 0.f, a3 = 0.f;
  float4 w0, w1, w2, w3;
  float4 h0, h1v, h2v, h3;
#define LDW(ws, q) ws.x = W3[((q) * 4 + 0) * DD + j];                        \
                   ws.y = W3[((q) * 4 + 1) * DD + j];                        \
                   ws.z = W3[((q) * 4 + 2) * DD + j];                        \
                   ws.w = W3[((q) * 4 + 3) * DD + j];
  LDW(w0, 0) LDW(w1, 1) LDW(w2, 2) LDW(w3, 3)
  h0  = *(const float4*)(hrow + 0);
  h1v = *(const float4*)(hrow + 4);
  h2v = *(const float4*)(hrow + 8);
  h3  = *(const float4*)(hrow + 12);
#define STEPB(hs, ws, qoff)                                                  \
  a0 = fmaf(hs.x, ws.x, a0); a1 = fmaf(hs.y, ws.y, a1);                      \
  a2 = fmaf(hs.z, ws.z, a2); a3 = fmaf(hs.w, ws.w, a3);                      \
  if (q4 != 31) {                                                            \
    LDW(ws, q4 * 4 + 4 + qoff)                                               \
    hs = *(const float4*)(hrow + (q4 * 4 + 4 + qoff) * 4);                   \
  }
  for (int q4 = 0; q4 < 32; ++q4) {
    STEPB(h0, w0, 0) STEPB(h1v, w1, 1) STEPB(h2v, w2, 2) STEPB(h3, w3, 3)
  }
#undef STEPB
#undef LDW
  float y = b3[j] + ((a0 + a1) + (a2 + a3));
  yB[row * DD + j] = y;
  if (do_trace) {
    float d = y - yA[row * DD + j];
    float g = 0.f;
#pragma unroll
    for (int k = 0; k < 8; ++k) {
      int vv = (k << 6) + j;
      float tv = T[row * HD + vv];
      g += (hrow[vv] > 0.f) ? tv : 0.f;
    }
    float val = fmaf(d, dtH, g * dt);
#pragma unroll
    for (int off = 32; off > 0; off >>= 1) val += __shfl_down(val, off);
    if (j == 0) logdet[row] -= val;
  }
}

// ---------------- pack outputs ----------------
__global__ __launch_bounds__(256) void k_out(const float* __restrict__ z,
    const float* __restrict__ logdet, float* __restrict__ out) {
  int i = blockIdx.x * 256 + threadIdx.x;     // 260*256 = 66560 exactly
  if (i < NB * DD) out[i] = z[i];
  else out[i] = logdet[i - NB * DD];
}

extern "C" void kernel_launch(void* const* d_in, const int* in_sizes, int n_in,
                              void* d_out, int out_size, void* d_ws, size_t ws_size,
                              hipStream_t stream) {
  const float* x  = (const float*)d_in[0];
  const float* W1 = (const float*)d_in[1];
  const float* b1 = (const float*)d_in[2];
  const float* W2 = (const float*)d_in[3];
  const float* b2 = (const float*)d_in[4];
  const float* W3 = (const float*)d_in[5];
  const float* b3 = (const float*)d_in[6];
  float* out = (float*)d_out;

  // ---- workspace layout ----
  short* sb = (short*)d_ws;
  short* W2h = sb;                         // 512*512
  short* W2l = W2h + HD * HD;
  short* Ep  = W2l + HD * HD;
  short* W1h = Ep  + HD * HD;              // 64*512
  short* W1l = W1h + DD * HD;
  short* send = W1l + DD * HD;             // 851968 shorts = 1703936 B (16-aligned)
  float* fb  = (float*)send;
  float* h2  = fb;                         // 1024*512
  float* T   = h2 + NB * HD;               // 1024*512
  float* zb0 = T + NB * HD;                // 1024*64
  float* zb1 = zb0 + NB * DD;
  float* y0  = zb1 + NB * DD;
  float* y1  = y0 + NB * DD;
  float* logdet = y1 + NB * DD;            // 1024  (total ~6.0 MB)

  float* zs[2] = {zb0, zb1};
  float* ys[2] = {y0, y1};

  k_prep<<<512, 512, 0, stream>>>(W1, W2, W3, W1h, W1l, W2h, W2l, Ep, logdet);

  // forward at z_0 = x (dt=0 => zb0 = x)
  k_step<<<256, 512, 0, stream>>>(x, zb0, x, 0.f, b1, b2,
                                  W1h, W1l, W2h, W2l, Ep, h2, T);
  k_step_b<<<256, 256, 0, stream>>>(h2, W3, b3, y0, y0, T, logdet, 0.f, 0.f, 0);

  double td[10];
  for (int i = 0; i < 10; ++i) td[i] = (double)i / 9.0;

  for (int t = 0; t < 9; ++t) {
    float dt  = (float)td[t + 1] - (float)td[t];
    float dtH = dt / 1e-5f;
    k_step<<<256, 512, 0, stream>>>(zs[t & 1], zs[(t + 1) & 1], ys[t & 1], dt,
                                    b1, b2, W1h, W1l, W2h, W2l, Ep, h2, T);
    k_step_b<<<256, 256, 0, stream>>>(h2, W3, b3, ys[(t + 1) & 1], ys[t & 1], T,
                                      logdet, dt, dtH, 1);
  }

  k_out<<<260, 256, 0, stream>>>(zs[1], logdet, out);
}

// Round 8
// 211.337 us; speedup vs baseline: 3.1057x; 1.3579x over previous
//
#include <hip/hip_runtime.h>

// NeuralODEFlow, slice-local formulation (13 launches):
//   trace_t = (S_{t+1}-S_t)*dt/H + g_{t+1}*dt,  S=sum_j mlp(z)_j, g=m1^T E m2
//   E[u,v] = W2[u,v]*(W3@W1)[v,u].  All GEMMs MFMA 16x16x32 bf16; y-path
//   (h1,h2,y) uses hi/lo 4-product split; E/T path single bf16.
// Launch k computes z_k (Euler from y_{k-1} partials), h-stack at z_k, and
// per-slice partials yPart/gPart; logdet for step t applied at launch t+2.

#define HD 512
#define DD 64
#define NB 1024

typedef __attribute__((ext_vector_type(8))) short short8;   // 8 bf16
typedef __attribute__((ext_vector_type(4))) float f32x4;

__device__ __forceinline__ unsigned short bf16_rn(float x) {
  unsigned int u = __float_as_uint(x);
  u += 0x7FFFu + ((u >> 16) & 1u);
  return (unsigned short)(u >> 16);
}
__device__ __forceinline__ float bf16_f(unsigned short h) {
  return __uint_as_float(((unsigned int)h) << 16);
}
#define MFMA(a, b, c) __builtin_amdgcn_mfma_f32_16x16x32_bf16(a, b, c, 0, 0, 0)

// ---------------- k_prep: pack W1/W2 (hi/lo), E, W3 (hi/lo); zero logdet ----
// grid 64 (kc 16 x kg 4), block 512 (nc 32 x nl 16). Every thread owns the
// 8 k's of one short8 fragment word -> all stores contiguous 16 B.
__global__ __launch_bounds__(512) void k_prep(const float* __restrict__ W1,
    const float* __restrict__ W2, const float* __restrict__ W3,
    short* __restrict__ W1h, short* __restrict__ W1l,
    short* __restrict__ W2h, short* __restrict__ W2l, short* __restrict__ Ep,
    short* __restrict__ W3h, short* __restrict__ W3l,
    float* __restrict__ logdet) {
  int bid = blockIdx.x;
  int kc = bid >> 2, kg = bid & 3;
  int tid = threadIdx.x;
  int nc = tid >> 4, nl = tid & 15;
  int u0 = kc * 32 + kg * 8;
  int n = nc * 16 + nl;
  if (bid < 2) logdet[bid * 512 + tid] = 0.f;
  // s[j] = K[v=n][u=u0+j] = sum_q W3[n][q] * W1[q][u0+j]
  float s[8];
#pragma unroll
  for (int j = 0; j < 8; ++j) s[j] = 0.f;
  for (int q = 0; q < DD; q += 4) {
    float4 w3q = *(const float4*)(W3 + n * DD + q);
#pragma unroll
    for (int i = 0; i < 4; ++i) {
      float wq = (i == 0) ? w3q.x : (i == 1) ? w3q.y : (i == 2) ? w3q.z : w3q.w;
      float4 a = *(const float4*)(W1 + (q + i) * HD + u0);
      float4 b = *(const float4*)(W1 + (q + i) * HD + u0 + 4);
      s[0] = fmaf(wq, a.x, s[0]); s[1] = fmaf(wq, a.y, s[1]);
      s[2] = fmaf(wq, a.z, s[2]); s[3] = fmaf(wq, a.w, s[3]);
      s[4] = fmaf(wq, b.x, s[4]); s[5] = fmaf(wq, b.y, s[5]);
      s[6] = fmaf(wq, b.z, s[6]); s[7] = fmaf(wq, b.w, s[7]);
    }
  }
  long off = ((long)(kc * 32 + nc) * 64 + kg * 16 + nl) * 8;
  short8 vh, vl, ve;
#pragma unroll
  for (int j = 0; j < 8; ++j) {
    float w2 = W2[(u0 + j) * HD + n];
    unsigned short uh = bf16_rn(w2);
    vh[j] = (short)uh;
    vl[j] = (short)bf16_rn(w2 - bf16_f(uh));
    ve[j] = (short)bf16_rn(w2 * s[j]);            // E[u][v]
  }
  *(short8*)(W2h + off) = vh;
  *(short8*)(W2l + off) = vl;
  *(short8*)(Ep + off) = ve;
  if (kc < 2) {                                    // W1: k = u0+j < 64
    short8 ah, al;
#pragma unroll
    for (int j = 0; j < 8; ++j) {
      float w1 = W1[(u0 + j) * HD + n];
      unsigned short uh = bf16_rn(w1);
      ah[j] = (short)uh;
      al[j] = (short)bf16_rn(w1 - bf16_f(uh));
    }
    *(short8*)(W1h + off) = ah;
    *(short8*)(W1l + off) = al;
  }
  if (nc < 4) {                                    // W3: k=v (8 of them), n=j<64
    long off3 = ((long)(kc * 4 + nc) * 64 + kg * 16 + nl) * 8;
    short8 th, tl;
#pragma unroll
    for (int sub = 0; sub < 8; ++sub) {
      float w3v = W3[(u0 + sub) * DD + n];
      unsigned short uh = bf16_rn(w3v);
      th[sub] = (short)uh;
      tl[sub] = (short)bf16_rn(w3v - bf16_f(uh));
    }
    *(short8*)(W3h + off3) = th;
    *(short8*)(W3l + off3) = tl;
  }
}

// ---------------- k_step: phase0 (Euler + S + logdet) -> h1 -> h2/T -> partials ----
// grid 256 = 64 rowgroups (16 rows) x 4 col-slices (128 v). 512 threads.
__global__ __launch_bounds__(512) void k_step(
    const float* __restrict__ zin, float* __restrict__ zout,
    const float* __restrict__ yPartR, const float* __restrict__ gR,
    const float* __restrict__ SRead, float* __restrict__ SWrite,
    float* __restrict__ logdet,
    const float* __restrict__ b1, const float* __restrict__ b2,
    const float* __restrict__ b3,
    const short* __restrict__ W1h, const short* __restrict__ W1l,
    const short* __restrict__ W2h, const short* __restrict__ W2l,
    const short* __restrict__ Ep,
    const short* __restrict__ W3h, const short* __restrict__ W3l,
    float* __restrict__ yPartW, float* __restrict__ gW,
    float dt, float dtp, float dtHp, int mode) {
  __shared__ __align__(16) short zh[16 * 72];
  __shared__ __align__(16) short zl[16 * 72];
  __shared__ __align__(16) short hh[16 * 520];
  __shared__ __align__(16) short hl[16 * 520];
  __shared__ __align__(16) short hm[16 * 520];
  __shared__ __align__(16) short h2h[16 * 136];
  __shared__ __align__(16) short h2l[16 * 136];
  __shared__ float gred[8 * 16];
  int bid = blockIdx.x;
  int cs = bid & 3;
  int r0 = (bid >> 2) << 4;
  int tid = threadIdx.x;
  int l = tid & 63;
  int w = tid >> 6;

  // ---- phase 0: y_{k-1} sum, Euler update, S, deferred logdet ----
#pragma unroll
  for (int half = 0; half < 2; ++half) {
    int rr = w + half * 8;
    int row = r0 + rr;
    float zv = zin[row * DD + l];
    float yv = 0.f;
    if (mode) {
      yv = yPartR[(0 * NB + row) * DD + l] + yPartR[(1 * NB + row) * DD + l] +
           yPartR[(2 * NB + row) * DD + l] + yPartR[(3 * NB + row) * DD + l] +
           b3[l];
      zv = fmaf(yv, dt, zv);
    }
    if (cs == 0) zout[row * DD + l] = zv;
    unsigned short hx = bf16_rn(zv);
    zh[rr * 72 + l] = (short)hx;
    zl[rr * 72 + l] = (short)bf16_rn(zv - bf16_f(hx));
    if (mode) {
      float sv = yv;
#pragma unroll
      for (int m = 1; m < 64; m <<= 1) sv += __shfl_xor(sv, m);
      if (l == 0 && cs == 0) {
        SWrite[row] = sv;                         // S_{k-1}
        if (mode == 2) {                          // apply scan-step k-2
          float g = gR[0 * NB + row] + gR[1 * NB + row] +
                    gR[2 * NB + row] + gR[3 * NB + row];
          logdet[row] -= (sv - SRead[row]) * dtHp + g * dtp;
        }
      }
    }
  }
  __syncthreads();

  // ---- phase 1: h1 = relu(z@W1+b1) (hi/lo/mask into LDS) ----
  {
    int mrow = l & 15;
    int kg = l >> 4;
    short8 az0h = *(const short8*)(zh + mrow * 72 + kg * 8);
    short8 az0l = *(const short8*)(zl + mrow * 72 + kg * 8);
    short8 az1h = *(const short8*)(zh + mrow * 72 + 32 + kg * 8);
    short8 az1l = *(const short8*)(zl + mrow * 72 + 32 + kg * 8);
    for (int i = 0; i < 4; ++i) {
      int nc = w * 4 + i;
      f32x4 acc = {0.f, 0.f, 0.f, 0.f};
      short8 b0h = *(const short8*)(W1h + ((long)(nc) * 64 + l) * 8);
      short8 b0l = *(const short8*)(W1l + ((long)(nc) * 64 + l) * 8);
      short8 c1h = *(const short8*)(W1h + ((long)(32 + nc) * 64 + l) * 8);
      short8 c1l = *(const short8*)(W1l + ((long)(32 + nc) * 64 + l) * 8);
      acc = MFMA(az0h, b0h, acc); acc = MFMA(az0h, b0l, acc);
      acc = MFMA(az0l, b0h, acc); acc = MFMA(az0l, b0l, acc);
      acc = MFMA(az1h, c1h, acc); acc = MFMA(az1h, c1l, acc);
      acc = MFMA(az1l, c1h, acc); acc = MFMA(az1l, c1l, acc);
      int n = nc * 16 + (l & 15);
      float bb = b1[n];
#pragma unroll
      for (int reg = 0; reg < 4; ++reg) {
        float h = fmaxf(acc[reg] + bb, 0.f);
        int r = (l >> 4) * 4 + reg;
        unsigned short uh = bf16_rn(h);
        unsigned short ul = bf16_rn(h - bf16_f(uh));
        unsigned short um = (h > 0.f) ? 0x3F80u : 0u;
        int ph = __shfl_xor((int)uh, 1);
        int pl = __shfl_xor((int)ul, 1);
        int pm = __shfl_xor((int)um, 1);
        if ((l & 1) == 0) {
          int base = r * 520 + n;
          *(unsigned int*)(hh + base) = (unsigned int)uh | (((unsigned int)(unsigned short)ph) << 16);
          *(unsigned int*)(hl + base) = (unsigned int)ul | (((unsigned int)(unsigned short)pl) << 16);
          *(unsigned int*)(hm + base) = (unsigned int)um | (((unsigned int)(unsigned short)pm) << 16);
        }
      }
    }
  }
  __syncthreads();

  // ---- phase 2: h2 = relu(h1@W2+b2), T = m1@E; epilogue: g-partials + h2->LDS ----
  {
    int mrow = l & 15;
    int kg = l >> 4;
    int ncg = cs * 8 + w;
    int n = ncg * 16 + mrow;
    f32x4 aH = {0.f, 0.f, 0.f, 0.f};
    f32x4 aT = {0.f, 0.f, 0.f, 0.f};
#pragma unroll 4
    for (int kc = 0; kc < 16; ++kc) {
      short8 Ah = *(const short8*)(hh + mrow * 520 + kc * 32 + kg * 8);
      short8 Al = *(const short8*)(hl + mrow * 520 + kc * 32 + kg * 8);
      short8 Am = *(const short8*)(hm + mrow * 520 + kc * 32 + kg * 8);
      long boff = ((long)(kc * 32 + ncg) * 64 + l) * 8;
      short8 Bh = *(const short8*)(W2h + boff);
      short8 Bl = *(const short8*)(W2l + boff);
      short8 Be = *(const short8*)(Ep + boff);
      aH = MFMA(Ah, Bh, aH); aH = MFMA(Ah, Bl, aH);
      aH = MFMA(Al, Bh, aH); aH = MFMA(Al, Bl, aH);
      aT = MFMA(Am, Be, aT);
    }
    float bb2 = b2[n];
    float h2v[4], gq[4];
#pragma unroll
    for (int reg = 0; reg < 4; ++reg) {
      float hv = aH[reg] + bb2;
      h2v[reg] = fmaxf(hv, 0.f);
      gq[reg] = (hv > 0.f) ? aT[reg] : 0.f;        // m2-gated T
    }
#pragma unroll
    for (int m = 1; m < 16; m <<= 1) {
#pragma unroll
      for (int reg = 0; reg < 4; ++reg) gq[reg] += __shfl_xor(gq[reg], m);
    }
    if ((l & 15) == 0) {
#pragma unroll
      for (int reg = 0; reg < 4; ++reg) gred[w * 16 + kg * 4 + reg] = gq[reg];
    }
#pragma unroll
    for (int reg = 0; reg < 4; ++reg) {            // h2 hi/lo -> LDS (A-layout)
      unsigned short uh = bf16_rn(h2v[reg]);
      unsigned short ul = bf16_rn(h2v[reg] - bf16_f(uh));
      int ph = __shfl_xor((int)uh, 1);
      int pl = __shfl_xor((int)ul, 1);
      if ((l & 1) == 0) {
        int rrow = kg * 4 + reg;
        int c = w * 16 + (l & 15);                 // col within slice (0..127)
        *(unsigned int*)(h2h + rrow * 136 + c) = (unsigned int)uh | (((unsigned int)(unsigned short)ph) << 16);
        *(unsigned int*)(h2l + rrow * 136 + c) = (unsigned int)ul | (((unsigned int)(unsigned short)pl) << 16);
      }
    }
  }
  __syncthreads();

  // ---- phase 3: yPart = h2_slice @ W3_slice (hi/lo MFMA); g combine ----
  if (w < 4) {                                     // wave w -> j-chunk w
    int mrow = l & 15;
    int kg = l >> 4;
    f32x4 ay = {0.f, 0.f, 0.f, 0.f};
#pragma unroll
    for (int kc = 0; kc < 4; ++kc) {
      short8 Ah = *(const short8*)(h2h + mrow * 136 + kc * 32 + kg * 8);
      short8 Al = *(const short8*)(h2l + mrow * 136 + kc * 32 + kg * 8);
      long b3off = (((long)(cs * 4 + kc) * 4 + w) * 64 + l) * 8;
      short8 Bh = *(const short8*)(W3h + b3off);
      short8 Bl = *(const short8*)(W3l + b3off);
      ay = MFMA(Ah, Bh, ay); ay = MFMA(Ah, Bl, ay);
      ay = MFMA(Al, Bh, ay); ay = MFMA(Al, Bl, ay);
    }
#pragma unroll
    for (int reg = 0; reg < 4; ++reg) {
      int row = r0 + kg * 4 + reg;
      yPartW[((long)cs * NB + row) * DD + w * 16 + mrow] = ay[reg];
    }
  } else if (w == 4) {
    if (l < 16) {
      float g = 0.f;
#pragma unroll
      for (int ww = 0; ww < 8; ++ww) g += gred[ww * 16 + l];
      gW[cs * NB + r0 + l] = g;
    }
  }
}

// ---------------- k_fin: apply last scan-step's logdet (t=8) ----------------
// grid 128 x 512: 8 rows/block, one wave per row.
__global__ __launch_bounds__(512) void k_fin(const float* __restrict__ yPartR,
    const float* __restrict__ gR, const float* __restrict__ SRead,
    const float* __restrict__ b3, float* __restrict__ logdet,
    float dtp, float dtHp) {
  int row = blockIdx.x * 8 + (threadIdx.x >> 6);
  int l = threadIdx.x & 63;
  float yv = yPartR[(0 * NB + row) * DD + l] + yPartR[(1 * NB + row) * DD + l] +
             yPartR[(2 * NB + row) * DD + l] + yPartR[(3 * NB + row) * DD + l] +
             b3[l];
  float sv = yv;
#pragma unroll
  for (int m = 1; m < 64; m <<= 1) sv += __shfl_xor(sv, m);
  if (l == 0) {
    float g = gR[0 * NB + row] + gR[1 * NB + row] +
              gR[2 * NB + row] + gR[3 * NB + row];
    logdet[row] -= (sv - SRead[row]) * dtHp + g * dtp;
  }
}

// ---------------- pack outputs ----------------
__global__ __launch_bounds__(256) void k_out(const float* __restrict__ z,
    const float* __restrict__ logdet, float* __restrict__ out) {
  int i = blockIdx.x * 256 + threadIdx.x;          // 260*256 = 66560 exactly
  if (i < NB * DD) out[i] = z[i];
  else out[i] = logdet[i - NB * DD];
}

extern "C" void kernel_launch(void* const* d_in, const int* in_sizes, int n_in,
                              void* d_out, int out_size, void* d_ws, size_t ws_size,
                              hipStream_t stream) {
  const float* x  = (const float*)d_in[0];
  const float* W1 = (const float*)d_in[1];
  const float* b1 = (const float*)d_in[2];
  const float* W2 = (const float*)d_in[3];
  const float* b2 = (const float*)d_in[4];
  const float* W3 = (const float*)d_in[5];
  const float* b3 = (const float*)d_in[6];
  float* out = (float*)d_out;

  // ---- workspace ----
  short* sb  = (short*)d_ws;
  short* W2h = sb;                                 // 512*512 each
  short* W2l = W2h + HD * HD;
  short* Ep  = W2l + HD * HD;
  short* W1h = Ep + HD * HD;                       // 64*512 each
  short* W1l = W1h + DD * HD;
  short* W3h = W1l + DD * HD;                      // 512*64 each
  short* W3l = W3h + HD * DD;
  float* fb  = (float*)(W3l + HD * DD);            // shorts total 16B-aligned
  float* yP0 = fb;                                 // [4][1024][64]
  float* yP1 = yP0 + 4 * NB * DD;
  float* gP0 = yP1 + 4 * NB * DD;                  // [4][1024]
  float* gP1 = gP0 + 4 * NB;
  float* SB0 = gP1 + 4 * NB;                       // [1024]
  float* SB1 = SB0 + NB;
  float* zb0 = SB1 + NB;                           // [1024][64]
  float* zb1 = zb0 + NB * DD;
  float* logdet = zb1 + NB * DD;                   // [1024]

  float* yP[2] = {yP0, yP1};
  float* gP[2] = {gP0, gP1};
  float* SB[2] = {SB0, SB1};
  float* zb[2] = {zb0, zb1};

  k_prep<<<64, 512, 0, stream>>>(W1, W2, W3, W1h, W1l, W2h, W2l, Ep, W3h, W3l,
                                 logdet);

  double td[10];
  for (int i = 0; i < 10; ++i) td[i] = (double)i / 9.0;
  float dts[9];
  for (int t = 0; t < 9; ++t) dts[t] = (float)td[t + 1] - (float)td[t];

  for (int k = 0; k <= 9; ++k) {
    const float* zi = (k == 0) ? x : zb[(k - 1) & 1];
    float dtc  = (k >= 1) ? dts[k - 1] : 0.f;
    float dtpv = (k >= 2) ? dts[k - 2] : 0.f;
    int mode = (k == 0) ? 0 : ((k == 1) ? 1 : 2);
    k_step<<<256, 512, 0, stream>>>(zi, zb[k & 1],
        yP[(k + 1) & 1], gP[(k + 1) & 1], SB[k & 1], SB[(k + 1) & 1], logdet,
        b1, b2, b3, W1h, W1l, W2h, W2l, Ep, W3h, W3l,
        yP[k & 1], gP[k & 1], dtc, dtpv, dtpv * 1e5f, mode);
  }
  // launch "10": apply scan-step t=8 (needs launch-9 outputs: yP[1], gP[1], SB[0]=S_8)
  k_fin<<<128, 512, 0, stream>>>(yP[1], gP[1], SB[0], b3, logdet,
                                 dts[8], dts[8] * 1e5f);

  k_out<<<260, 256, 0, stream>>>(zb[1], logdet, out);
}